// Round 3
// baseline (185.325 us; speedup 1.0000x reference)
//
#include <hip/hip_runtime.h>
#include <hip/hip_bf16.h>
#include <stdint.h>

// ---------------------------------------------------------------------------
// SelfAttention fused pipeline. Device buffers are FP32 (per reference);
// compute path converts to bf16 for MFMA, accumulates fp32.
//   K0: convert x, qkv_w, proj_w fp32 -> bf16 workspace copies
//   K1: qkv = x @ qkv_w^T (+RoPE on q,k, fp32 sin/cos) -> q/k/v ws [B,H,N,64] bf16
//   K2: flash attention per (b,h)                       -> aws [B,N,768] bf16
//   K3: out = aws @ proj_w^T + proj_b (fp32)            -> d_out [B,N,768] fp32
// B=2 N=2048 D=768 H=12 Dh=64, M=4096, E3=2304. No tail cases.
// ---------------------------------------------------------------------------

typedef unsigned short u16;
typedef __attribute__((ext_vector_type(8))) short s16x8;   // 8 x bf16 (4 VGPRs)
typedef __attribute__((ext_vector_type(4))) float f32x4;   // MFMA accumulator

#define MFMA16(a, b, c) __builtin_amdgcn_mfma_f32_16x16x32_bf16((a), (b), (c), 0, 0, 0)

__device__ __forceinline__ u16 f2bf(float f) {  // round-to-nearest-even
    uint32_t u = __float_as_uint(f);
    u = u + 0x7fffu + ((u >> 16) & 1u);
    return (u16)(u >> 16);
}

// ---------------------------------------------------------------------------
// K0: fp32 -> bf16 elementwise convert (n divisible by 4).
// ---------------------------------------------------------------------------
__global__ __launch_bounds__(256)
void k_cvt(const float* __restrict__ src, u16* __restrict__ dst, int n4)
{
    const int i = blockIdx.x * 256 + threadIdx.x;
    if (i < n4) {
        const float4 v = ((const float4*)src)[i];
        ushort4 o;
        o.x = f2bf(v.x); o.y = f2bf(v.y); o.z = f2bf(v.z); o.w = f2bf(v.w);
        ((ushort4*)dst)[i] = o;
    }
}

// ---------------------------------------------------------------------------
// K1: QKV GEMM (128x128 tile, BK=32) with fused RoPE epilogue.
// grid (32, 18), 256 threads (4 waves, 2x2 wave grid, 64x64 per wave).
// ---------------------------------------------------------------------------
__global__ __launch_bounds__(256, 2)
void k_qkv_rope(const u16* __restrict__ X,     // [4096][768] bf16
                const u16* __restrict__ W,     // [2304][768] bf16
                const float* __restrict__ SIN, // [2048][64] fp32
                const float* __restrict__ COS, // [2048][64] fp32
                u16* __restrict__ qws, u16* __restrict__ kws, u16* __restrict__ vws)
{
    __shared__ u16 As[128 * 32];
    __shared__ u16 Bs[128 * 32];
    const int t  = threadIdx.x;
    const int l  = t & 63;
    const int w  = t >> 6;
    const int cl = l & 15, gh = l >> 4;
    const int brow = blockIdx.x * 128;
    const int bcol = blockIdx.y * 128;
    const int wr = (w >> 1) * 64;
    const int wc = (w & 1) * 64;

    // staging map: lane l covers tile row (w*16 + l/4), 8-elem chunk (l&3)
    const int srow = w * 16 + (l >> 2);
    const int scol = (l & 3) * 8;
    const u16* gA = X + (size_t)(brow + srow) * 768 + scol;
    const u16* gB = W + (size_t)(bcol + srow) * 768 + scol;

    f32x4 acc[4][4] = {};

    for (int kt = 0; kt < 24; ++kt) {
        const int k0 = kt * 32;
        const s16x8 a0 = *(const s16x8*)(gA + k0);
        const s16x8 a1 = *(const s16x8*)(gA + k0 + 64 * 768);
        const s16x8 b0 = *(const s16x8*)(gB + k0);
        const s16x8 b1 = *(const s16x8*)(gB + k0 + 64 * 768);
        __syncthreads();   // previous iteration's readers done
        *(s16x8*)(As + srow * 32 + scol)        = a0;
        *(s16x8*)(As + (srow + 64) * 32 + scol) = a1;
        *(s16x8*)(Bs + srow * 32 + scol)        = b0;
        *(s16x8*)(Bs + (srow + 64) * 32 + scol) = b1;
        __syncthreads();   // writes visible

        s16x8 af[4], bv[4];
        #pragma unroll
        for (int m = 0; m < 4; ++m)
            af[m] = *(const s16x8*)(As + (wr + m * 16 + cl) * 32 + gh * 8);
        #pragma unroll
        for (int n = 0; n < 4; ++n)
            bv[n] = *(const s16x8*)(Bs + (wc + n * 16 + cl) * 32 + gh * 8);
        #pragma unroll
        for (int m = 0; m < 4; ++m)
            #pragma unroll
            for (int n = 0; n < 4; ++n)
                acc[m][n] = MFMA16(af[m], bv[n], acc[m][n]);
    }

    // Epilogue: wave covers cols [bcol+wc, +64) == exactly one head segment.
    const int seg   = (bcol + wc) >> 6;   // 0..35
    const int which = seg / 12;           // 0:q 1:k 2:v
    const int h     = seg % 12;
    u16* outp = (which == 0) ? qws : (which == 1) ? kws : vws;

    #pragma unroll
    for (int m = 0; m < 4; ++m) {
        #pragma unroll
        for (int jj = 0; jj < 4; ++jj) {
            const int row = brow + wr + m * 16 + gh * 4 + jj;  // 0..4095
            const int b   = row >> 11;
            const int tok = row & 2047;
            u16* orow = outp + ((size_t)(b * 12 + h) * 2048 + tok) * 64;
            if (which == 2) {
                #pragma unroll
                for (int n = 0; n < 4; ++n)
                    orow[n * 16 + cl] = f2bf(acc[m][n][jj]);
            } else {
                const float* srow2 = SIN + tok * 64;
                const float* crow2 = COS + tok * 64;
                #pragma unroll
                for (int n = 0; n < 4; ++n) {
                    const int dh = n * 16 + cl;
                    // rotate_half: dh<32 -> -t[dh+32] (frag n+2); dh>=32 -> +t[dh-32]
                    const float v = acc[m][n][jj];
                    const float partner = (n < 2) ? -acc[m][n + 2][jj] : acc[m][n - 2][jj];
                    orow[dh] = f2bf(v * crow2[dh] + partner * srow2[dh]);
                }
            }
        }
    }
}

// ---------------------------------------------------------------------------
// K2: flash attention. grid (16, 24) = (q-tiles of 128, b*H). 4 waves x 32 rows.
// KV tile = 64. K frags from global (L2-resident); V transposed into LDS with
// XOR swizzle; P round-trips through per-wave swizzled LDS (C-layout->A-layout).
// ---------------------------------------------------------------------------
__global__ __launch_bounds__(256, 2)
void k_attn(const u16* __restrict__ Qg, const u16* __restrict__ Kg,
            const u16* __restrict__ Vg, u16* __restrict__ Og)
{
    __shared__ u16 Vt[64 * 64];        // [dh][kk] swizzled, 8KB
    __shared__ u16 Pl[4][32 * 64];     // per-wave P, swizzled, 16KB
    const int t  = threadIdx.x;
    const int l  = t & 63;
    const int w  = t >> 6;
    const int cl = l & 15, gh = l >> 4;
    const int bh = blockIdx.y;                     // 0..23
    const int qb = blockIdx.x * 128 + w * 32;      // this wave's first q row
    const u16* Q = Qg + (size_t)bh * 2048 * 64;
    const u16* K = Kg + (size_t)bh * 2048 * 64;
    const u16* V = Vg + (size_t)bh * 2048 * 64;

    // Q fragments live in registers for the whole kernel.
    s16x8 qf[2][2];
    #pragma unroll
    for (int m = 0; m < 2; ++m)
        #pragma unroll
        for (int ks = 0; ks < 2; ++ks)
            qf[m][ks] = *(const s16x8*)(Q + (qb + m * 16 + cl) * 64 + ks * 32 + gh * 8);

    f32x4 acc[2][4] = {};
    float mrun[2][4], lrun[2][4];
    #pragma unroll
    for (int m = 0; m < 2; ++m)
        #pragma unroll
        for (int jj = 0; jj < 4; ++jj) { mrun[m][jj] = -3e38f; lrun[m][jj] = 0.f; }

    const int vr  = t >> 2;         // 0..63 (V row within tile)
    const int dh0 = (t & 3) * 16;
    u16* myP = Pl[w];

    for (int kt = 0; kt < 32; ++kt) {
        const int kvb = kt * 64;
        // ---- stage V^T into LDS (swizzled: byte ^= (row&7)<<4) ----
        {
            const u16* vp = V + (size_t)(kvb + vr) * 64 + dh0;
            s16x8 va = *(const s16x8*)vp;
            s16x8 vb = *(const s16x8*)(vp + 8);
            #pragma unroll
            for (int j = 0; j < 8; ++j) {
                const int d1 = dh0 + j;
                *(u16*)((char*)Vt + ((d1 * 128 + vr * 2) ^ ((d1 & 7) << 4))) = (u16)va[j];
                const int d2 = dh0 + 8 + j;
                *(u16*)((char*)Vt + ((d2 * 128 + vr * 2) ^ ((d2 & 7) << 4))) = (u16)vb[j];
            }
        }
        __syncthreads();

        // ---- S = Q K^T (K frags straight from global) ----
        f32x4 s[2][4] = {};
        #pragma unroll
        for (int nk = 0; nk < 4; ++nk) {
            #pragma unroll
            for (int ks = 0; ks < 2; ++ks) {
                const s16x8 kf = *(const s16x8*)(K + (size_t)(kvb + nk * 16 + cl) * 64 + ks * 32 + gh * 8);
                #pragma unroll
                for (int m = 0; m < 2; ++m)
                    s[m][nk] = MFMA16(qf[m][ks], kf, s[m][nk]);
            }
        }

        // ---- online softmax (row stats across the 16-lane col group) ----
        #pragma unroll
        for (int m = 0; m < 2; ++m) {
            #pragma unroll
            for (int jj = 0; jj < 4; ++jj) {
                float pm = fmaxf(fmaxf(s[m][0][jj], s[m][1][jj]),
                                 fmaxf(s[m][2][jj], s[m][3][jj])) * 0.125f;
                #pragma unroll
                for (int off = 1; off < 16; off <<= 1)
                    pm = fmaxf(pm, __shfl_xor(pm, off));
                const float mnew  = fmaxf(mrun[m][jj], pm);
                const float alpha = __expf(mrun[m][jj] - mnew);
                float sum = 0.f;
                #pragma unroll
                for (int nk = 0; nk < 4; ++nk) {
                    const float p = __expf(s[m][nk][jj] * 0.125f - mnew);
                    s[m][nk][jj] = p;
                    sum += p;
                }
                #pragma unroll
                for (int off = 1; off < 16; off <<= 1)
                    sum += __shfl_xor(sum, off);
                lrun[m][jj] = lrun[m][jj] * alpha + sum;
                mrun[m][jj] = mnew;
                #pragma unroll
                for (int n = 0; n < 4; ++n) acc[m][n][jj] *= alpha;
            }
        }

        // ---- P (C-layout) -> LDS bf16, swizzled ----
        #pragma unroll
        for (int m = 0; m < 2; ++m) {
            #pragma unroll
            for (int jj = 0; jj < 4; ++jj) {
                const int row = m * 16 + gh * 4 + jj;
                const int sw  = (row & 7) << 4;
                #pragma unroll
                for (int nk = 0; nk < 4; ++nk)
                    *(u16*)((char*)myP + ((row * 128 + (nk * 16 + cl) * 2) ^ sw)) =
                        f2bf(s[m][nk][jj]);
            }
        }

        // ---- PV: read P in A-layout, Vt in B-layout, accumulate O ----
        #pragma unroll
        for (int ks = 0; ks < 2; ++ks) {
            s16x8 pa[2];
            #pragma unroll
            for (int m = 0; m < 2; ++m) {
                const int row = m * 16 + cl;
                pa[m] = *(const s16x8*)((char*)myP +
                        ((row * 128 + (ks * 32 + gh * 8) * 2) ^ ((row & 7) << 4)));
            }
            #pragma unroll
            for (int n = 0; n < 4; ++n) {
                const int dr = n * 16 + cl;
                const s16x8 vf = *(const s16x8*)((char*)Vt +
                        ((dr * 128 + (ks * 32 + gh * 8) * 2) ^ ((dr & 7) << 4)));
                #pragma unroll
                for (int m = 0; m < 2; ++m)
                    acc[m][n] = MFMA16(pa[m], vf, acc[m][n]);
            }
        }
        __syncthreads();
    }

    // ---- epilogue: O / l, write [B,N,H*64] bf16 ----
    const int b = bh / 12, h = bh % 12;
    #pragma unroll
    for (int m = 0; m < 2; ++m) {
        #pragma unroll
        for (int jj = 0; jj < 4; ++jj) {
            const int row = qb + m * 16 + gh * 4 + jj;       // 0..2047
            const float inv = 1.0f / lrun[m][jj];
            u16* orow = Og + ((size_t)(b * 2048 + row)) * 768 + h * 64;
            #pragma unroll
            for (int n = 0; n < 4; ++n)
                orow[n * 16 + cl] = f2bf(acc[m][n][jj] * inv);
        }
    }
}

// ---------------------------------------------------------------------------
// K3: output projection + bias (fp32 out). grid (32, 6), same structure as K1.
// ---------------------------------------------------------------------------
__global__ __launch_bounds__(256, 2)
void k_proj(const u16* __restrict__ A,      // [4096][768] bf16
            const u16* __restrict__ W,      // [768][768] bf16
            const float* __restrict__ BIAS, // [768] fp32
            float* __restrict__ OUT)        // [4096][768] fp32
{
    __shared__ u16 As[128 * 32];
    __shared__ u16 Bs[128 * 32];
    const int t  = threadIdx.x;
    const int l  = t & 63;
    const int w  = t >> 6;
    const int cl = l & 15, gh = l >> 4;
    const int brow = blockIdx.x * 128;
    const int bcol = blockIdx.y * 128;
    const int wr = (w >> 1) * 64;
    const int wc = (w & 1) * 64;

    const int srow = w * 16 + (l >> 2);
    const int scol = (l & 3) * 8;
    const u16* gA = A + (size_t)(brow + srow) * 768 + scol;
    const u16* gB = W + (size_t)(bcol + srow) * 768 + scol;

    f32x4 acc[4][4] = {};

    for (int kt = 0; kt < 24; ++kt) {
        const int k0 = kt * 32;
        const s16x8 a0 = *(const s16x8*)(gA + k0);
        const s16x8 a1 = *(const s16x8*)(gA + k0 + 64 * 768);
        const s16x8 b0 = *(const s16x8*)(gB + k0);
        const s16x8 b1 = *(const s16x8*)(gB + k0 + 64 * 768);
        __syncthreads();
        *(s16x8*)(As + srow * 32 + scol)        = a0;
        *(s16x8*)(As + (srow + 64) * 32 + scol) = a1;
        *(s16x8*)(Bs + srow * 32 + scol)        = b0;
        *(s16x8*)(Bs + (srow + 64) * 32 + scol) = b1;
        __syncthreads();

        s16x8 af[4], bv[4];
        #pragma unroll
        for (int m = 0; m < 4; ++m)
            af[m] = *(const s16x8*)(As + (wr + m * 16 + cl) * 32 + gh * 8);
        #pragma unroll
        for (int n = 0; n < 4; ++n)
            bv[n] = *(const s16x8*)(Bs + (wc + n * 16 + cl) * 32 + gh * 8);
        #pragma unroll
        for (int m = 0; m < 4; ++m)
            #pragma unroll
            for (int n = 0; n < 4; ++n)
                acc[m][n] = MFMA16(af[m], bv[n], acc[m][n]);
    }

    #pragma unroll
    for (int m = 0; m < 4; ++m) {
        #pragma unroll
        for (int jj = 0; jj < 4; ++jj) {
            const int row = brow + wr + m * 16 + gh * 4 + jj;
            #pragma unroll
            for (int n = 0; n < 4; ++n) {
                const int col = bcol + wc + n * 16 + cl;
                OUT[(size_t)row * 768 + col] = acc[m][n][jj] + BIAS[col];
            }
        }
    }
}

// ---------------------------------------------------------------------------
extern "C" void kernel_launch(void* const* d_in, const int* in_sizes, int n_in,
                              void* d_out, int out_size, void* d_ws, size_t ws_size,
                              hipStream_t stream)
{
    const float* x     = (const float*)d_in[0];
    const float* sinp  = (const float*)d_in[1];
    const float* cosp  = (const float*)d_in[2];
    const float* qkv_w = (const float*)d_in[3];
    const float* projw = (const float*)d_in[4];
    const float* projb = (const float*)d_in[5];
    float* out = (float*)d_out;

    // workspace (all u16/bf16):
    //   xbf [4096*768] | wqkv [2304*768] | wproj [768*768]
    //   qws/kws/vws [2*12*2048*64] each | aws [4096*768]
    const size_t N_X  = (size_t)4096 * 768;   // 3,145,728
    const size_t N_WQ = (size_t)2304 * 768;   // 1,769,472
    const size_t N_WP = (size_t)768 * 768;    //   589,824
    const size_t SEG  = (size_t)2 * 12 * 2048 * 64;  // 3,145,728

    u16* xbf   = (u16*)d_ws;
    u16* wqkv  = xbf + N_X;
    u16* wproj = wqkv + N_WQ;
    u16* qws   = wproj + N_WP;
    u16* kws   = qws + SEG;
    u16* vws   = kws + SEG;
    u16* aws   = vws + SEG;   // total ~36.2 MB

    k_cvt<<<(int)(N_X  / 4 + 255) / 256, 256, 0, stream>>>(x,     xbf,   (int)(N_X  / 4));
    k_cvt<<<(int)(N_WQ / 4 + 255) / 256, 256, 0, stream>>>(qkv_w, wqkv,  (int)(N_WQ / 4));
    k_cvt<<<(int)(N_WP / 4 + 255) / 256, 256, 0, stream>>>(projw, wproj, (int)(N_WP / 4));

    k_qkv_rope<<<dim3(32, 18), 256, 0, stream>>>(xbf, wqkv, sinp, cosp, qws, kws, vws);
    k_attn    <<<dim3(16, 24), 256, 0, stream>>>(qws, kws, vws, aws);
    k_proj    <<<dim3(32, 6),  256, 0, stream>>>(aws, wproj, projb, out);
}

// Round 4
// 165.975 us; speedup vs baseline: 1.1166x; 1.1166x over previous
//
#include <hip/hip_runtime.h>
#include <hip/hip_bf16.h>
#include <stdint.h>

// ---------------------------------------------------------------------------
// SelfAttention fused pipeline. FP32 device buffers; bf16 MFMA, fp32 accum.
//   K0: convert x, qkv_w, proj_w fp32 -> bf16 workspace
//   K1: qkv = x @ qkv_w^T (+RoPE) -> q,k [B,H,N,64]; V TRANSPOSED [B,H,64,N]
//   K2: flash attention, zero-LDS swapped-MFMA form   -> aws [B,N,768] bf16
//   K3: out = aws @ proj_w^T + proj_b (fp32)          -> d_out fp32
// B=2 N=2048 D=768 H=12 Dh=64.
// ---------------------------------------------------------------------------

typedef unsigned short u16;
typedef __attribute__((ext_vector_type(8))) short s16x8;   // 8 x bf16 (4 VGPRs)
typedef __attribute__((ext_vector_type(4))) float f32x4;   // MFMA accumulator

#define MFMA16(a, b, c) __builtin_amdgcn_mfma_f32_16x16x32_bf16((a), (b), (c), 0, 0, 0)

__device__ __forceinline__ u16 f2bf(float f) {  // round-to-nearest-even
    uint32_t u = __float_as_uint(f);
    u = u + 0x7fffu + ((u >> 16) & 1u);
    return (u16)(u >> 16);
}
__device__ __forceinline__ uint32_t pk2(float lo, float hi) {
    return (uint32_t)f2bf(lo) | ((uint32_t)f2bf(hi) << 16);
}

// ---------------------------------------------------------------------------
// K0: fp32 -> bf16 elementwise convert (n divisible by 4).
// ---------------------------------------------------------------------------
__global__ __launch_bounds__(256)
void k_cvt(const float* __restrict__ src, u16* __restrict__ dst, int n4)
{
    const int i = blockIdx.x * 256 + threadIdx.x;
    if (i < n4) {
        const float4 v = ((const float4*)src)[i];
        ushort4 o;
        o.x = f2bf(v.x); o.y = f2bf(v.y); o.z = f2bf(v.z); o.w = f2bf(v.w);
        ((ushort4*)dst)[i] = o;
    }
}

// ---------------------------------------------------------------------------
// K1: QKV GEMM (128x128 tile, BK=32) with fused RoPE epilogue.
// grid (32, 18), 256 threads. V is written TRANSPOSED: vws[b,h,dh,tok].
// ---------------------------------------------------------------------------
__global__ __launch_bounds__(256, 2)
void k_qkv_rope(const u16* __restrict__ X,     // [4096][768] bf16
                const u16* __restrict__ W,     // [2304][768] bf16
                const float* __restrict__ SIN, // [2048][64] fp32
                const float* __restrict__ COS, // [2048][64] fp32
                u16* __restrict__ qws, u16* __restrict__ kws, u16* __restrict__ vtws)
{
    __shared__ u16 As[128 * 32];
    __shared__ u16 Bs[128 * 32];
    const int t  = threadIdx.x;
    const int l  = t & 63;
    const int w  = t >> 6;
    const int cl = l & 15, gh = l >> 4;
    const int brow = blockIdx.x * 128;
    const int bcol = blockIdx.y * 128;
    const int wr = (w >> 1) * 64;
    const int wc = (w & 1) * 64;

    const int srow = w * 16 + (l >> 2);
    const int scol = (l & 3) * 8;
    const u16* gA = X + (size_t)(brow + srow) * 768 + scol;
    const u16* gB = W + (size_t)(bcol + srow) * 768 + scol;

    f32x4 acc[4][4] = {};

    for (int kt = 0; kt < 24; ++kt) {
        const int k0 = kt * 32;
        const s16x8 a0 = *(const s16x8*)(gA + k0);
        const s16x8 a1 = *(const s16x8*)(gA + k0 + 64 * 768);
        const s16x8 b0 = *(const s16x8*)(gB + k0);
        const s16x8 b1 = *(const s16x8*)(gB + k0 + 64 * 768);
        __syncthreads();
        *(s16x8*)(As + srow * 32 + scol)        = a0;
        *(s16x8*)(As + (srow + 64) * 32 + scol) = a1;
        *(s16x8*)(Bs + srow * 32 + scol)        = b0;
        *(s16x8*)(Bs + (srow + 64) * 32 + scol) = b1;
        __syncthreads();

        s16x8 af[4], bv[4];
        #pragma unroll
        for (int m = 0; m < 4; ++m)
            af[m] = *(const s16x8*)(As + (wr + m * 16 + cl) * 32 + gh * 8);
        #pragma unroll
        for (int n = 0; n < 4; ++n)
            bv[n] = *(const s16x8*)(Bs + (wc + n * 16 + cl) * 32 + gh * 8);
        #pragma unroll
        for (int m = 0; m < 4; ++m)
            #pragma unroll
            for (int n = 0; n < 4; ++n)
                acc[m][n] = MFMA16(af[m], bv[n], acc[m][n]);
    }

    const int seg   = (bcol + wc) >> 6;   // 0..35
    const int which = seg / 12;           // 0:q 1:k 2:v
    const int h     = seg % 12;

    #pragma unroll
    for (int m = 0; m < 4; ++m) {
        #pragma unroll
        for (int jj = 0; jj < 4; ++jj) {
            const int row = brow + wr + m * 16 + gh * 4 + jj;  // 0..4095
            const int b   = row >> 11;
            const int tok = row & 2047;
            if (which == 2) {
                // transposed V: vtws[b,h,dh,tok]
                u16* vtb = vtws + (size_t)(b * 12 + h) * 64 * 2048;
                #pragma unroll
                for (int n = 0; n < 4; ++n)
                    vtb[(size_t)(n * 16 + cl) * 2048 + tok] = f2bf(acc[m][n][jj]);
            } else {
                u16* outp = (which == 0) ? qws : kws;
                u16* orow = outp + ((size_t)(b * 12 + h) * 2048 + tok) * 64;
                const float* srow2 = SIN + tok * 64;
                const float* crow2 = COS + tok * 64;
                #pragma unroll
                for (int n = 0; n < 4; ++n) {
                    const int dh = n * 16 + cl;
                    const float v = acc[m][n][jj];
                    const float partner = (n < 2) ? -acc[m][n + 2][jj] : acc[m][n - 2][jj];
                    orow[dh] = f2bf(v * crow2[dh] + partner * srow2[dh]);
                }
            }
        }
    }
}

// ---------------------------------------------------------------------------
// K2: zero-LDS flash attention. grid 768 x 128 threads (2 waves x 32 q-rows).
// Swapped QK^T (S^T = K x Q) -> lane-local softmax (q = lane&15);
// in-register P^T rearrange -> PV as O^T = V^T x P^T, V^T frags from global.
// bh-grouped block swizzle keeps 3 heads' K/V per XCD L2.
// ---------------------------------------------------------------------------
__global__ __launch_bounds__(128)
void k_attn(const u16* __restrict__ Qg, const u16* __restrict__ Kg,
            const u16* __restrict__ VTg, u16* __restrict__ Og)
{
    const int t  = threadIdx.x;
    const int l  = t & 63;
    const int w  = t >> 6;
    const int cl = l & 15, gh = l >> 4;

    // bijective swizzle: XCD (= i%8, assumed) owns 3 consecutive heads
    const int i  = blockIdx.x;                  // 0..767
    const int bh = (i & 7) * 3 + ((i >> 3) % 3);
    const int qt = i / 24;                      // 0..31
    const int qb = qt * 64 + w * 32;            // this wave's first q row

    const u16* Q  = Qg  + (size_t)bh * 2048 * 64;
    const u16* K  = Kg  + (size_t)bh * 2048 * 64;
    const u16* VT = VTg + (size_t)bh * 64 * 2048;

    // Q B-fragments: lane holds col q = qb+m*16+cl, rows dh = ks*32+gh*8+j
    s16x8 qf[2][2];
    #pragma unroll
    for (int m = 0; m < 2; ++m)
        #pragma unroll
        for (int ks = 0; ks < 2; ++ks)
            qf[m][ks] = *(const s16x8*)(Q + (size_t)(qb + m * 16 + cl) * 64 + ks * 32 + gh * 8);

    f32x4 o[2][4] = {};            // O^T tiles: lane col q=cl, row dh=n*16+gh*4+jj
    float mrun[2] = { -3e38f, -3e38f };
    float lrun[2] = { 0.f, 0.f };

    const int srcA = cl + (gh & 1) * 32;   // P^T rearrange source lanes
    const int srcB = srcA + 16;
    const bool loGH = (gh < 2);

    for (int kt = 0; kt < 32; ++kt) {
        const int kvb = kt * 64;

        // ---- S^T = K x Q (A = K frag: row k=cl, cols dh contiguous) ----
        f32x4 st[2][4] = {};
        #pragma unroll
        for (int nk = 0; nk < 4; ++nk) {
            #pragma unroll
            for (int ks = 0; ks < 2; ++ks) {
                const s16x8 kf = *(const s16x8*)(K + (size_t)(kvb + nk * 16 + cl) * 64 + ks * 32 + gh * 8);
                st[0][nk] = MFMA16(kf, qf[0][ks], st[0][nk]);
                st[1][nk] = MFMA16(kf, qf[1][ks], st[1][nk]);
            }
        }

        // ---- lane-local online softmax (lane owns q = qb+m*16+cl) ----
        uint32_t d[2][4][2];
        #pragma unroll
        for (int m = 0; m < 2; ++m) {
            float pm = st[m][0][0];
            #pragma unroll
            for (int nk = 0; nk < 4; ++nk)
                #pragma unroll
                for (int jj = 0; jj < 4; ++jj)
                    pm = fmaxf(pm, st[m][nk][jj]);
            pm *= 0.125f;
            pm = fmaxf(pm, __shfl_xor(pm, 16));
            pm = fmaxf(pm, __shfl_xor(pm, 32));
            const float mnew  = fmaxf(mrun[m], pm);
            const float alpha = __expf(mrun[m] - mnew);
            float sum = 0.f;
            #pragma unroll
            for (int nk = 0; nk < 4; ++nk)
                #pragma unroll
                for (int jj = 0; jj < 4; ++jj) {
                    const float p = __expf(st[m][nk][jj] * 0.125f - mnew);
                    st[m][nk][jj] = p;
                    sum += p;
                }
            sum += __shfl_xor(sum, 16);
            sum += __shfl_xor(sum, 32);
            lrun[m] = lrun[m] * alpha + sum;
            mrun[m] = mnew;
            #pragma unroll
            for (int n = 0; n < 4; ++n)
                #pragma unroll
                for (int jj = 0; jj < 4; ++jj)
                    o[m][n][jj] *= alpha;
            // pack P^T rows (k = nk*16+gh*4+jj) to bf16 dword pairs
            #pragma unroll
            for (int nk = 0; nk < 4; ++nk) {
                d[m][nk][0] = pk2(st[m][nk][0], st[m][nk][1]);
                d[m][nk][1] = pk2(st[m][nk][2], st[m][nk][3]);
            }
        }

        // ---- per 32-k window: rearrange P^T to B-frag, PV MFMA ----
        #pragma unroll
        for (int ks = 0; ks < 2; ++ks) {
            s16x8 pa[2];
            #pragma unroll
            for (int m = 0; m < 2; ++m) {
                const uint32_t e0 = d[m][2 * ks][0],     e1 = d[m][2 * ks][1];
                const uint32_t o0 = d[m][2 * ks + 1][0], o1 = d[m][2 * ks + 1][1];
                const uint32_t xE0 = (uint32_t)__shfl((int)e0, srcA);
                const uint32_t xE1 = (uint32_t)__shfl((int)e1, srcA);
                const uint32_t xE2 = (uint32_t)__shfl((int)e0, srcB);
                const uint32_t xE3 = (uint32_t)__shfl((int)e1, srcB);
                const uint32_t xO0 = (uint32_t)__shfl((int)o0, srcA);
                const uint32_t xO1 = (uint32_t)__shfl((int)o1, srcA);
                const uint32_t xO2 = (uint32_t)__shfl((int)o0, srcB);
                const uint32_t xO3 = (uint32_t)__shfl((int)o1, srcB);
                union { s16x8 v; uint32_t u[4]; } asm_;
                asm_.u[0] = loGH ? xE0 : xO0;
                asm_.u[1] = loGH ? xE1 : xO1;
                asm_.u[2] = loGH ? xE2 : xO2;
                asm_.u[3] = loGH ? xE3 : xO3;
                pa[m] = asm_.v;
            }
            #pragma unroll
            for (int n = 0; n < 4; ++n) {
                const s16x8 va = *(const s16x8*)(VT + (size_t)(n * 16 + cl) * 2048 + kvb + ks * 32 + gh * 8);
                o[0][n] = MFMA16(va, pa[0], o[0][n]);
                o[1][n] = MFMA16(va, pa[1], o[1][n]);
            }
        }
    }

    // ---- epilogue: O^T/l -> aws[b, tok, h*64+dh], vectorized 8B stores ----
    const int b = bh / 12, h = bh % 12;
    #pragma unroll
    for (int m = 0; m < 2; ++m) {
        const float inv = 1.0f / lrun[m];
        const int row = qb + m * 16 + cl;
        u16* orow = Og + ((size_t)(b * 2048 + row)) * 768 + h * 64;
        #pragma unroll
        for (int n = 0; n < 4; ++n) {
            uint2 pkv;
            pkv.x = pk2(o[m][n][0] * inv, o[m][n][1] * inv);
            pkv.y = pk2(o[m][n][2] * inv, o[m][n][3] * inv);
            *(uint2*)(orow + n * 16 + gh * 4) = pkv;
        }
    }
}

// ---------------------------------------------------------------------------
// K3: output projection + bias (fp32 out). grid (32, 6).
// ---------------------------------------------------------------------------
__global__ __launch_bounds__(256, 2)
void k_proj(const u16* __restrict__ A,      // [4096][768] bf16
            const u16* __restrict__ W,      // [768][768] bf16
            const float* __restrict__ BIAS, // [768] fp32
            float* __restrict__ OUT)        // [4096][768] fp32
{
    __shared__ u16 As[128 * 32];
    __shared__ u16 Bs[128 * 32];
    const int t  = threadIdx.x;
    const int l  = t & 63;
    const int w  = t >> 6;
    const int cl = l & 15, gh = l >> 4;
    const int brow = blockIdx.x * 128;
    const int bcol = blockIdx.y * 128;
    const int wr = (w >> 1) * 64;
    const int wc = (w & 1) * 64;

    const int srow = w * 16 + (l >> 2);
    const int scol = (l & 3) * 8;
    const u16* gA = A + (size_t)(brow + srow) * 768 + scol;
    const u16* gB = W + (size_t)(bcol + srow) * 768 + scol;

    f32x4 acc[4][4] = {};

    for (int kt = 0; kt < 24; ++kt) {
        const int k0 = kt * 32;
        const s16x8 a0 = *(const s16x8*)(gA + k0);
        const s16x8 a1 = *(const s16x8*)(gA + k0 + 64 * 768);
        const s16x8 b0 = *(const s16x8*)(gB + k0);
        const s16x8 b1 = *(const s16x8*)(gB + k0 + 64 * 768);
        __syncthreads();
        *(s16x8*)(As + srow * 32 + scol)        = a0;
        *(s16x8*)(As + (srow + 64) * 32 + scol) = a1;
        *(s16x8*)(Bs + srow * 32 + scol)        = b0;
        *(s16x8*)(Bs + (srow + 64) * 32 + scol) = b1;
        __syncthreads();

        s16x8 af[4], bv[4];
        #pragma unroll
        for (int m = 0; m < 4; ++m)
            af[m] = *(const s16x8*)(As + (wr + m * 16 + cl) * 32 + gh * 8);
        #pragma unroll
        for (int n = 0; n < 4; ++n)
            bv[n] = *(const s16x8*)(Bs + (wc + n * 16 + cl) * 32 + gh * 8);
        #pragma unroll
        for (int m = 0; m < 4; ++m)
            #pragma unroll
            for (int n = 0; n < 4; ++n)
                acc[m][n] = MFMA16(af[m], bv[n], acc[m][n]);
    }

    #pragma unroll
    for (int m = 0; m < 4; ++m) {
        #pragma unroll
        for (int jj = 0; jj < 4; ++jj) {
            const int row = brow + wr + m * 16 + gh * 4 + jj;
            #pragma unroll
            for (int n = 0; n < 4; ++n) {
                const int col = bcol + wc + n * 16 + cl;
                OUT[(size_t)row * 768 + col] = acc[m][n][jj] + BIAS[col];
            }
        }
    }
}

// ---------------------------------------------------------------------------
extern "C" void kernel_launch(void* const* d_in, const int* in_sizes, int n_in,
                              void* d_out, int out_size, void* d_ws, size_t ws_size,
                              hipStream_t stream)
{
    const float* x     = (const float*)d_in[0];
    const float* sinp  = (const float*)d_in[1];
    const float* cosp  = (const float*)d_in[2];
    const float* qkv_w = (const float*)d_in[3];
    const float* projw = (const float*)d_in[4];
    const float* projb = (const float*)d_in[5];
    float* out = (float*)d_out;

    const size_t N_X  = (size_t)4096 * 768;
    const size_t N_WQ = (size_t)2304 * 768;
    const size_t N_WP = (size_t)768 * 768;
    const size_t SEG  = (size_t)2 * 12 * 2048 * 64;

    u16* xbf   = (u16*)d_ws;
    u16* wqkv  = xbf + N_X;
    u16* wproj = wqkv + N_WQ;
    u16* qws   = wproj + N_WP;
    u16* kws   = qws + SEG;
    u16* vtws  = kws + SEG;   // transposed V [B,H,64,2048]
    u16* aws   = vtws + SEG;

    k_cvt<<<(int)(N_X  / 4 + 255) / 256, 256, 0, stream>>>(x,     xbf,   (int)(N_X  / 4));
    k_cvt<<<(int)(N_WQ / 4 + 255) / 256, 256, 0, stream>>>(qkv_w, wqkv,  (int)(N_WQ / 4));
    k_cvt<<<(int)(N_WP / 4 + 255) / 256, 256, 0, stream>>>(projw, wproj, (int)(N_WP / 4));

    k_qkv_rope<<<dim3(32, 18), 256, 0, stream>>>(xbf, wqkv, sinp, cosp, qws, kws, vtws);
    k_attn    <<<768, 128, 0, stream>>>(qws, kws, vtws, aws);
    k_proj    <<<dim3(32, 6),  256, 0, stream>>>(aws, wproj, projb, out);
}